// Round 12
// baseline (16.275 us; speedup 1.0000x reference)
//
#include <hip/hip_runtime.h>
#include <math.h>

typedef float f32x2 __attribute__((ext_vector_type(2)));
typedef unsigned long long u64;

#define L_RES 512
#define N_BATCH 64
#define NTHR 512                          // 8 waves per block
#define BLK_PER_B 4                       // blocks per batch
#define NBLOCKS (N_BATCH * BLK_PER_B)     // 256 blocks = 1 per CU, 8 waves/CU
#define R_ROWS 8                          // rows held in registers per thread
#define JSTRIDE 32                        // 4 blocks x 8 waves = 32 phases -> 16 j-iters
#define FLAG_PAT 0xCCCCCCCCu              // != 0xAAAAAAAA poison, != 0
#define TAG_STRIDE 8                      // u64s -> 64 B between tagged words

// Identity: 2 * sum_{i<j} (din-dtg)^2  ==  sum over ALL ordered (i,j) of
//   [ sq_in + sq_tg - 2*sqrt(sq_in*sq_tg) ]   (diagonal contributes 0).
//
// R11 change (isolated): finalizer = LAST-dispatched hw block (NBLOCKS-1)
// instead of block 0. Block 0 is dispatched first, finishes first, and was
// idle-polling for the whole dispatch-ramp skew (~1-1.5us). The last block
// finishes last, so everyone else's tags are already visible when it polls
// -> the ramp skew hides inside its own compute. Dispatch order is a perf
// heuristic only: ANY block is a correct finalizer (it polls all 256 tags);
// unexpected ordering degrades to R10 behavior, never breaks.
//
// Tagged-payload completion (R9, any-initial-state sound): each block
// publishes (FLAG_PAT<<32)|f32_bits(partial) with one release store at a
// 64B-strided private address; finalizer polls with acquire loads (readiness
// and payload in one word), sums in fixed order (bit-deterministic), writes
// out, clears tags. Writers never wait -> deadlock-free.
//
// XCD-aware decode (R8): b = blockIdx & 63 puts a batch's 4 blocks on the
// same XCD (XCD = blockIdx % 8) -> one L2 copy per batch, 32 blocks/XCD.

__global__ __launch_bounds__(NTHR) void rgn_fused_kernel(
    const float* __restrict__ inp, const float* __restrict__ tgt,
    u64* __restrict__ tagged,      // [NBLOCKS * TAG_STRIDE], logical id b*4+q
    float* __restrict__ out)
{
    __shared__ f32x2 sx[L_RES];     // (input.x, target.x) per residue
    __shared__ f32x2 sy[L_RES];
    __shared__ f32x2 sz[L_RES];
    __shared__ float wsum[NTHR / 64];

    const int bhw  = blockIdx.x;
    const int b    = bhw & 63;        // batch id (same XCD for all its blocks)
    const int q    = bhw >> 6;        // block-within-batch 0..3
    const int lid  = b * BLK_PER_B + q;  // logical block id
    const int t    = threadIdx.x;
    const int lane = t & 63;
    const int wv   = t >> 6;          // wave 0..7

    const float* __restrict__ binp = inp + (size_t)b * L_RES * 9;
    const float* __restrict__ btgt = tgt + (size_t)b * L_RES * 9;

    // stage CA atom (atom 1 -> floats 3..5 of each residue's 9); 1 residue/thread
    for (int l = t; l < L_RES; l += NTHR) {
        sx[l] = (f32x2){binp[l*9+3], btgt[l*9+3]};
        sy[l] = (f32x2){binp[l*9+4], btgt[l*9+4]};
        sz[l] = (f32x2){binp[l*9+5], btgt[l*9+5]};
    }
    __syncthreads();

    // 8 rows per thread, strided by 64: i = lane + 64*r
    f32x2 rx[R_ROWS], ry[R_ROWS], rz[R_ROWS];
    #pragma unroll
    for (int r = 0; r < R_ROWS; ++r) {
        const int i = lane + 64 * r;
        rx[r] = sx[i]; ry[r] = sy[i]; rz[r] = sz[i];
    }

    f32x2 asq = (f32x2){0.0f, 0.0f};   // sum of (sq_in, sq_tg)
    float acx = 0.0f;                   // sum of sqrt(sq_in*sq_tg)

    const int ph = q * 8 + wv;                     // 0..31
    for (int j = ph; j < L_RES; j += JSTRIDE) {    // 16 iterations
        const f32x2 jx = sx[j], jy = sy[j], jz = sz[j];  // wave-uniform broadcast
        #pragma unroll
        for (int r = 0; r < R_ROWS; ++r) {
            f32x2 dx = rx[r] - jx;
            f32x2 dy = ry[r] - jy;
            f32x2 dz = rz[r] - jz;
            f32x2 sq = __builtin_elementwise_fma(dz, dz,
                        __builtin_elementwise_fma(dy, dy, dx * dx));
            asq += sq;
            acx += __builtin_amdgcn_sqrtf(sq.x * sq.y);
        }
    }

    // per-thread combine, then block reduce (8 waves)
    float a = (asq.x + asq.y) - 2.0f * acx;
    for (int o = 32; o > 0; o >>= 1) a += __shfl_down(a, o);
    if (lane == 0) wsum[wv] = a;
    __syncthreads();

    if (t == 0) {
        float s = ((((((wsum[0] + wsum[1]) + wsum[2]) + wsum[3])
                      + wsum[4]) + wsum[5]) + wsum[6]) + wsum[7];
        u64 v = ((u64)FLAG_PAT << 32) | (u64)__float_as_uint(s);
        __hip_atomic_store(&tagged[lid * TAG_STRIDE], v, __ATOMIC_RELEASE,
                           __HIP_MEMORY_SCOPE_AGENT);
    }

    // LAST-dispatched hw block, wave 0: sole finalizer (poll exits ~immediately)
    if (bhw == NBLOCKS - 1 && t < 64) {
        // lane t = batch t: poll the 4 tagged words it will consume
        u64 v[BLK_PER_B];
        for (;;) {
            bool ready = true;
            #pragma unroll
            for (int k = 0; k < BLK_PER_B; ++k) {
                v[k] = __hip_atomic_load(&tagged[(t * BLK_PER_B + k) * TAG_STRIDE],
                                         __ATOMIC_ACQUIRE,
                                         __HIP_MEMORY_SCOPE_AGENT);
                ready &= ((unsigned)(v[k] >> 32) == FLAG_PAT);
            }
            if (__all(ready)) break;
            __builtin_amdgcn_s_sleep(2);
        }
        // ordered sum of batch t's 4 partials (payload = low 32 bits)
        float ss = 0.0f;
        #pragma unroll
        for (int k = 0; k < BLK_PER_B; ++k)
            ss += __uint_as_float((unsigned)(v[k] & 0xFFFFFFFFull));
        // ss = 2 * sum_{i<j} (din-dtg)^2 for batch t
        float r = sqrtf(ss + 1e-6f) * (1.0f / (sqrtf(512.0f * 511.0f) * 512.0f));
        for (int o = 32; o > 0; o >>= 1) r += __shfl_down(r, o);
        if (t == 0) out[0] = r * (1.0f / (float)N_BATCH);
        // clear tags for the next stream-ordered call
        #pragma unroll
        for (int k = 0; k < BLK_PER_B; ++k)
            __hip_atomic_store(&tagged[(t * BLK_PER_B + k) * TAG_STRIDE], 0ull,
                               __ATOMIC_RELAXED, __HIP_MEMORY_SCOPE_AGENT);
    }
}

extern "C" void kernel_launch(void* const* d_in, const int* in_sizes, int n_in,
                              void* d_out, int out_size, void* d_ws, size_t ws_size,
                              hipStream_t stream) {
    const float* inp = (const float*)d_in[0];   // [N,3,3] f32
    const float* tgt = (const float*)d_in[1];   // [N,3,3] f32
    u64*   tagged = (u64*)d_ws;                 // 256 x 64B-strided tagged words
    float* out    = (float*)d_out;

    rgn_fused_kernel<<<NBLOCKS, NTHR, 0, stream>>>(inp, tgt, tagged, out);
}